// Round 11
// baseline (155.554 us; speedup 1.0000x reference)
//
#include <hip/hip_runtime.h>
#include <hip/hip_bf16.h>
#include <cstdint>
#include <cstddef>
#include <math.h>

#define D 256
#define TEMP_INV 2.0f       // 1 / TEMPERATURE, TEMPERATURE = 0.5
#define EPS_NORM 1e-8f
#define NTILES 2080         // 64*65/2 upper-triangular 128x128 tiles

typedef __attribute__((ext_vector_type(8))) short bf16x8;
typedef __attribute__((ext_vector_type(4))) float f32x4;

// ---------------- kernel 1: normalize rows, write bf16 zn ----------------
__global__ void __launch_bounds__(256) normalize_rows(
    const float* __restrict__ zi, const float* __restrict__ zj,
    __hip_bfloat16* __restrict__ zn, float* __restrict__ denom,
    unsigned* __restrict__ counter, int B) {
  const int wid = threadIdx.x >> 6;
  const int lane = threadIdx.x & 63;
  if (threadIdx.x < 16) denom[blockIdx.x * 16 + threadIdx.x] = 0.0f;
  if (blockIdx.x == 0 && threadIdx.x == 0) *counter = 0u;
#pragma unroll
  for (int it = 0; it < 4; ++it) {
    int row = it * 2048 + blockIdx.x * 4 + wid;
    const float* src = (row < B) ? (zi + (size_t)row * D)
                                 : (zj + (size_t)(row - B) * D);
    float4 v = ((const float4*)src)[lane];
    float ss = v.x * v.x + v.y * v.y + v.z * v.z + v.w * v.w;
    for (int off = 32; off; off >>= 1) ss += __shfl_xor(ss, off);
    float rn = 1.0f / fmaxf(sqrtf(ss), EPS_NORM);
    union { ushort4 u; __hip_bfloat16 h[4]; } o;
    o.h[0] = __float2bfloat16(v.x * rn);
    o.h[1] = __float2bfloat16(v.y * rn);
    o.h[2] = __float2bfloat16(v.z * rn);
    o.h[3] = __float2bfloat16(v.w * rn);
    ((ushort4*)zn)[(size_t)row * (D / 4) + lane] = o.u;
  }
}

// ---------------- kernel 2: fused sim GEMM, BK=32 / 16 KB LDS ------------
// 128x128 upper-tri tile per block, 2080 blocks. Footprint shrunk vs R8
// (32->16 KB LDS) to double resident independent blocks per CU — R1/R3/R8
// all pinned at ~14.3k CU-cycles/tile with every pipe <20% busy, i.e.
// concurrency-limited, so residency is THE lever. Staging: lane-sequential
// coalesced float4 loads (R8-proven), ds_write with XOR swizzle
// chunk' = c ^ ((row>>1)&3) on 64B rows: both write and frag-read are
// capacity-minimum 2-way per 16-lane phase (the regime that measured 0
// conflicts in R4/R6-R8). Named-scalar staging lifetimes (no-spill shape).
// Loss finalize fused via last-block ticket (worked in R10, saves a launch).
__device__ __forceinline__ void decode_tile(int t, int Nb, int& by, int& bx) {
  float fb = (2.0f * Nb + 1.0f -
              sqrtf((float)((2 * Nb + 1) * (2 * Nb + 1) - 8 * t))) * 0.5f;
  int y = (int)fb;
  while ((y + 1) * Nb - ((y + 1) * y) / 2 <= t) ++y;
  while (y * Nb - (y * (y - 1)) / 2 > t) --y;
  by = y;
  bx = y + (t - (y * Nb - (y * (y - 1)) / 2));
}

__global__ void __launch_bounds__(256) ntxent_gemm(
    const __hip_bfloat16* __restrict__ zn, float* __restrict__ denom,
    float* __restrict__ pos, unsigned* __restrict__ counter,
    float* __restrict__ out, int B) {
  __shared__ __align__(16) __hip_bfloat16 Ash[128 * 32];  // 8 KB
  __shared__ __align__(16) __hip_bfloat16 Bsh[128 * 32];  // 8 KB
  __shared__ unsigned ticket_s;
  __shared__ float red_s[4];

  const int N = 2 * B;
  const int Nb = N / 128;  // 64
  int by, bx;
  decode_tile(blockIdx.x, Nb, by, bx);
  const int bm = by * 128;
  const int bn = bx * 128;
  const bool isDiag = (by == bx);
  const bool isPos = (bx == by + B / 128);

  const int tid = threadIdx.x;
  const int wid = tid >> 6;
  const int lane = tid & 63;
  const int wy = wid >> 1, wx = wid & 1;
  const int wrow0 = wid * 32;

  // staging: lane -> (row16 = lane>>2 in [0,16), c4 = lane&3 16B chunk)
  // two row-groups s=0,1 at rows wrow0 + s*16 + row16
  const int row16 = lane >> 2;
  const int c4 = lane & 3;
  const int swz = (c4 ^ ((row16 >> 1) & 3)) * 8;  // element offset in 32-wide row

  const int frow = lane & 15;
  const int quad = lane >> 4;
  const int chunkoff = (quad ^ ((frow >> 1) & 3)) * 8;

  f32x4 acc[4][4] = {};

  const __hip_bfloat16* gA = zn + (size_t)(bm + wrow0 + row16) * D + c4 * 8;
  const __hip_bfloat16* gB = zn + (size_t)(bn + wrow0 + row16) * D + c4 * 8;
  const int la = (wrow0 + row16) * 32 + swz;  // s=0; s=1 at +16*32

#pragma unroll
  for (int ki = 0; ki < 8; ++ki) {
    const int k0 = ki * 32;
    // coalesced loads; named scalars, in-iteration lifetime (no-spill shape)
    float4 va0 = *(const float4*)(gA + k0);
    float4 va1 = *(const float4*)(gA + 16 * D + k0);
    float4 vb0 = *(const float4*)(gB + k0);
    float4 vb1 = *(const float4*)(gB + 16 * D + k0);
    __syncthreads();  // WAR: previous slab's LDS reads complete
    *(float4*)&Ash[la] = va0;
    *(float4*)&Ash[la + 16 * 32] = va1;
    *(float4*)&Bsh[la] = vb0;
    *(float4*)&Bsh[la + 16 * 32] = vb1;
    __syncthreads();
    bf16x8 a[4], b[4];
#pragma unroll
    for (int i = 0; i < 4; ++i)
      a[i] = *(const bf16x8*)&Ash[(wy * 64 + i * 16 + frow) * 32 + chunkoff];
#pragma unroll
    for (int j = 0; j < 4; ++j)
      b[j] = *(const bf16x8*)&Bsh[(wx * 64 + j * 16 + frow) * 32 + chunkoff];
#pragma unroll
    for (int i = 0; i < 4; ++i)
#pragma unroll
      for (int j = 0; j < 4; ++j)
        acc[i][j] =
            __builtin_amdgcn_mfma_f32_16x16x32_bf16(a[i], b[j], acc[i][j], 0, 0, 0);
  }

  // epilogue: C/D layout col = lane&15, row = quad*4 + reg
  const int colq = lane & 15;
  float cs[4] = {0.0f, 0.0f, 0.0f, 0.0f};
#pragma unroll
  for (int i = 0; i < 4; ++i) {
#pragma unroll
    for (int r = 0; r < 4; ++r) {
      int row = bm + wy * 64 + i * 16 + quad * 4 + r;
      float rs = 0.0f;
#pragma unroll
      for (int j = 0; j < 4; ++j) {
        int col = bn + wx * 64 + j * 16 + colq;
        float v = acc[i][j][r];
        float e = __expf(v * TEMP_INV);
        e = (isDiag && col == row) ? 0.0f : e;
        rs += e;
        cs[j] += e;
        if (isPos && col == row + B) { pos[row] = v; pos[col] = v; }
      }
      rs += __shfl_xor(rs, 1);
      rs += __shfl_xor(rs, 2);
      rs += __shfl_xor(rs, 4);
      rs += __shfl_xor(rs, 8);
      if (colq == 0) atomicAdd(&denom[row], rs);
    }
  }
  if (!isDiag) {
#pragma unroll
    for (int j = 0; j < 4; ++j) {
      float c = cs[j];
      c += __shfl_xor(c, 16);
      c += __shfl_xor(c, 32);
      if (quad == 0) atomicAdd(&denom[bn + wx * 64 + j * 16 + colq], c);
    }
  }

  // -------- last block to finish computes the loss (device-scope fence) --
  __syncthreads();
  if (tid == 0) {
    __threadfence();                      // release: publish pos/denom
    ticket_s = atomicAdd(counter, 1u);
  }
  __syncthreads();
  if (ticket_s == NTILES - 1) {
    __threadfence();                      // acquire: see all blocks' writes
    float s = 0.0f;
    for (int i = tid; i < N / 4; i += 256) {
      float4 d = ((const float4*)denom)[i];
      float4 p = ((const float4*)pos)[i];
      s += __logf(d.x) - p.x * TEMP_INV;
      s += __logf(d.y) - p.y * TEMP_INV;
      s += __logf(d.z) - p.z * TEMP_INV;
      s += __logf(d.w) - p.w * TEMP_INV;
    }
    for (int off = 32; off; off >>= 1) s += __shfl_xor(s, off);
    if (lane == 0) red_s[wid] = s;
    __syncthreads();
    if (tid == 0)
      out[0] = (red_s[0] + red_s[1] + red_s[2] + red_s[3]) / (float)N;
  }
}

extern "C" void kernel_launch(void* const* d_in, const int* in_sizes, int n_in,
                              void* d_out, int out_size, void* d_ws, size_t ws_size,
                              hipStream_t stream) {
  const float* zi = (const float*)d_in[0];
  const float* zj = (const float*)d_in[1];
  const int B = in_sizes[0] / D;  // 4096
  const int N = 2 * B;            // 8192

  __hip_bfloat16* zn = (__hip_bfloat16*)d_ws;
  float* denom = (float*)((char*)d_ws + (size_t)N * D * sizeof(__hip_bfloat16));
  float* pos = denom + N;
  unsigned* counter = (unsigned*)(pos + N);

  normalize_rows<<<512, 256, 0, stream>>>(zi, zj, zn, denom, counter, B);
  ntxent_gemm<<<NTILES, 256, 0, stream>>>(zn, denom, pos, counter,
                                          (float*)d_out, B);
}

// Round 12
// 149.120 us; speedup vs baseline: 1.0431x; 1.0431x over previous
//
#include <hip/hip_runtime.h>
#include <hip/hip_bf16.h>
#include <cstdint>
#include <cstddef>
#include <math.h>

#define D 256
#define TEMP_INV 2.0f       // 1 / TEMPERATURE, TEMPERATURE = 0.5
#define EPS_NORM 1e-8f
#define NTILES 2080         // 64*65/2 upper-triangular 128x128 tiles

typedef __attribute__((ext_vector_type(8))) short bf16x8;
typedef __attribute__((ext_vector_type(4))) float f32x4;

// ---------------- kernel 1: normalize rows, write bf16 zn ----------------
__global__ void __launch_bounds__(256) normalize_rows(
    const float* __restrict__ zi, const float* __restrict__ zj,
    __hip_bfloat16* __restrict__ zn, float* __restrict__ denom,
    unsigned* __restrict__ counter, int B) {
  const int wid = threadIdx.x >> 6;
  const int lane = threadIdx.x & 63;
  if (threadIdx.x < 16) denom[blockIdx.x * 16 + threadIdx.x] = 0.0f;
  if (blockIdx.x == 0 && threadIdx.x == 0) *counter = 0u;
#pragma unroll
  for (int it = 0; it < 4; ++it) {
    int row = it * 2048 + blockIdx.x * 4 + wid;
    const float* src = (row < B) ? (zi + (size_t)row * D)
                                 : (zj + (size_t)(row - B) * D);
    float4 v = ((const float4*)src)[lane];
    float ss = v.x * v.x + v.y * v.y + v.z * v.z + v.w * v.w;
    for (int off = 32; off; off >>= 1) ss += __shfl_xor(ss, off);
    float rn = 1.0f / fmaxf(sqrtf(ss), EPS_NORM);
    union { ushort4 u; __hip_bfloat16 h[4]; } o;
    o.h[0] = __float2bfloat16(v.x * rn);
    o.h[1] = __float2bfloat16(v.y * rn);
    o.h[2] = __float2bfloat16(v.z * rn);
    o.h[3] = __float2bfloat16(v.w * rn);
    ((ushort4*)zn)[(size_t)row * (D / 4) + lane] = o.u;
  }
}

// ---------------- kernel 2: double-buffered fused sim GEMM ---------------
// 128x128 upper-tri tile per block, BK=64, LDS DOUBLE-BUFFERED (64 KB):
// one barrier per K-iter; next slab's coalesced float4 loads are issued
// before compute and consumed by ds_write after it, so global latency and
// the LDS turnaround leave the serial chain (the ~3.6k-cycle/iter wall
// measured across R1/R3/R8/R11). Staging keeps R8's proven pieces:
// lane-sequential loads (TA-mergeable), XOR swizzle on the ds_write LDS
// address (0 conflicts R4/R6-R8), named scalars only (no cross-barrier
// aggregates: the R2/R6/R7 scratch-spill shape). Ticket finalize (R10).
__device__ __forceinline__ void decode_tile(int t, int Nb, int& by, int& bx) {
  float fb = (2.0f * Nb + 1.0f -
              sqrtf((float)((2 * Nb + 1) * (2 * Nb + 1) - 8 * t))) * 0.5f;
  int y = (int)fb;
  while ((y + 1) * Nb - ((y + 1) * y) / 2 <= t) ++y;
  while (y * Nb - (y * (y - 1)) / 2 > t) --y;
  by = y;
  bx = y + (t - (y * Nb - (y * (y - 1)) / 2));
}

__device__ __forceinline__ void mfma_slab(
    const __hip_bfloat16* __restrict__ As, const __hip_bfloat16* __restrict__ Bs,
    f32x4 acc[4][4], int wy, int wx, int frow, int quad, int f7) {
#pragma unroll
  for (int kk = 0; kk < 2; ++kk) {
    bf16x8 a[4], b[4];
#pragma unroll
    for (int i = 0; i < 4; ++i)
      a[i] = *(const bf16x8*)
          &As[(wy * 64 + i * 16 + frow) * 64 + ((kk * 4 + quad) ^ f7) * 8];
#pragma unroll
    for (int j = 0; j < 4; ++j)
      b[j] = *(const bf16x8*)
          &Bs[(wx * 64 + j * 16 + frow) * 64 + ((kk * 4 + quad) ^ f7) * 8];
#pragma unroll
    for (int i = 0; i < 4; ++i)
#pragma unroll
      for (int j = 0; j < 4; ++j)
        acc[i][j] =
            __builtin_amdgcn_mfma_f32_16x16x32_bf16(a[i], b[j], acc[i][j], 0, 0, 0);
  }
}

#define LOAD_SLAB(v, base, k0)                         \
  v##0 = *(const float4*)((base) + 0 * 8 * D + (k0));  \
  v##1 = *(const float4*)((base) + 1 * 8 * D + (k0));  \
  v##2 = *(const float4*)((base) + 2 * 8 * D + (k0));  \
  v##3 = *(const float4*)((base) + 3 * 8 * D + (k0));

#define WRITE_SLAB(v, lds)                         \
  *(float4*)&(lds)[ldsoff + 0 * 8 * 64] = v##0;    \
  *(float4*)&(lds)[ldsoff + 1 * 8 * 64] = v##1;    \
  *(float4*)&(lds)[ldsoff + 2 * 8 * 64] = v##2;    \
  *(float4*)&(lds)[ldsoff + 3 * 8 * 64] = v##3;

__global__ void __launch_bounds__(256, 2) ntxent_gemm(
    const __hip_bfloat16* __restrict__ zn, float* __restrict__ denom,
    float* __restrict__ pos, unsigned* __restrict__ counter,
    float* __restrict__ out, int B) {
  __shared__ __align__(16) __hip_bfloat16 Ash[2][128 * 64];  // 32 KB
  __shared__ __align__(16) __hip_bfloat16 Bsh[2][128 * 64];  // 32 KB
  __shared__ unsigned ticket_s;
  __shared__ float red_s[4];

  const int N = 2 * B;
  const int Nb = N / 128;  // 64
  int by, bx;
  decode_tile(blockIdx.x, Nb, by, bx);
  const int bm = by * 128;
  const int bn = bx * 128;
  const bool isDiag = (by == bx);
  const bool isPos = (bx == by + B / 128);

  const int tid = threadIdx.x;
  const int wid = tid >> 6;
  const int lane = tid & 63;
  const int wy = wid >> 1, wx = wid & 1;
  const int wrow0 = wid * 32;

  const int lr = lane >> 3;     // staging row within 8-row group (== r&7)
  const int c8 = lane & 7;      // 16B chunk, SEQUENTIAL in global memory
  const int frow = lane & 15;
  const int quad = lane >> 4;
  const int f7 = frow & 7;

  f32x4 acc[4][4] = {};

  const __hip_bfloat16* gA = zn + (size_t)(bm + wrow0 + lr) * D + c8 * 8;
  const __hip_bfloat16* gB = zn + (size_t)(bn + wrow0 + lr) * D + c8 * 8;
  const int ldsoff = (wrow0 + lr) * 64 + (c8 ^ lr) * 8;

  float4 va0, va1, va2, va3, vb0, vb1, vb2, vb3;  // staging set X
  float4 wa0, wa1, wa2, wa3, wb0, wb1, wb2, wb3;  // staging set Y

  // prologue: slab0 -> buf0; slab1 loads in flight across the barrier
  LOAD_SLAB(va, gA, 0) LOAD_SLAB(vb, gB, 0)
  WRITE_SLAB(va, Ash[0]) WRITE_SLAB(vb, Bsh[0])
  LOAD_SLAB(va, gA, 64) LOAD_SLAB(vb, gB, 64)
  __syncthreads();

  // ki=0: compute buf0; slab2 -> set Y in flight; write slab1 -> buf1
  LOAD_SLAB(wa, gA, 128) LOAD_SLAB(wb, gB, 128)
  mfma_slab(Ash[0], Bsh[0], acc, wy, wx, frow, quad, f7);
  WRITE_SLAB(va, Ash[1]) WRITE_SLAB(vb, Bsh[1])
  __syncthreads();

  // ki=1: compute buf1; slab3 -> set X in flight; write slab2 -> buf0
  LOAD_SLAB(va, gA, 192) LOAD_SLAB(vb, gB, 192)
  mfma_slab(Ash[1], Bsh[1], acc, wy, wx, frow, quad, f7);
  WRITE_SLAB(wa, Ash[0]) WRITE_SLAB(wb, Bsh[0])
  __syncthreads();

  // ki=2: compute buf0; write slab3 -> buf1
  mfma_slab(Ash[0], Bsh[0], acc, wy, wx, frow, quad, f7);
  WRITE_SLAB(va, Ash[1]) WRITE_SLAB(vb, Bsh[1])
  __syncthreads();

  // ki=3: compute buf1
  mfma_slab(Ash[1], Bsh[1], acc, wy, wx, frow, quad, f7);

  // epilogue: C/D layout col = lane&15, row = quad*4 + reg
  const int colq = lane & 15;
  float cs[4] = {0.0f, 0.0f, 0.0f, 0.0f};
#pragma unroll
  for (int i = 0; i < 4; ++i) {
#pragma unroll
    for (int r = 0; r < 4; ++r) {
      int row = bm + wy * 64 + i * 16 + quad * 4 + r;
      float rs = 0.0f;
#pragma unroll
      for (int j = 0; j < 4; ++j) {
        int col = bn + wx * 64 + j * 16 + colq;
        float v = acc[i][j][r];
        float e = __expf(v * TEMP_INV);
        e = (isDiag && col == row) ? 0.0f : e;
        rs += e;
        cs[j] += e;
        if (isPos && col == row + B) { pos[row] = v; pos[col] = v; }
      }
      rs += __shfl_xor(rs, 1);
      rs += __shfl_xor(rs, 2);
      rs += __shfl_xor(rs, 4);
      rs += __shfl_xor(rs, 8);
      if (colq == 0) atomicAdd(&denom[row], rs);
    }
  }
  if (!isDiag) {
#pragma unroll
    for (int j = 0; j < 4; ++j) {
      float c = cs[j];
      c += __shfl_xor(c, 16);
      c += __shfl_xor(c, 32);
      if (quad == 0) atomicAdd(&denom[bn + wx * 64 + j * 16 + colq], c);
    }
  }

  // -------- last block to finish computes the loss (device-scope fence) --
  __syncthreads();
  if (tid == 0) {
    __threadfence();                      // release: publish pos/denom
    ticket_s = atomicAdd(counter, 1u);
  }
  __syncthreads();
  if (ticket_s == NTILES - 1) {
    __threadfence();                      // acquire: see all blocks' writes
    float s = 0.0f;
    for (int i = tid; i < N / 4; i += 256) {
      float4 d = ((const float4*)denom)[i];
      float4 p = ((const float4*)pos)[i];
      s += __logf(d.x) - p.x * TEMP_INV;
      s += __logf(d.y) - p.y * TEMP_INV;
      s += __logf(d.z) - p.z * TEMP_INV;
      s += __logf(d.w) - p.w * TEMP_INV;
    }
    for (int off = 32; off; off >>= 1) s += __shfl_xor(s, off);
    if (lane == 0) red_s[wid] = s;
    __syncthreads();
    if (tid == 0)
      out[0] = (red_s[0] + red_s[1] + red_s[2] + red_s[3]) / (float)N;
  }
}

extern "C" void kernel_launch(void* const* d_in, const int* in_sizes, int n_in,
                              void* d_out, int out_size, void* d_ws, size_t ws_size,
                              hipStream_t stream) {
  const float* zi = (const float*)d_in[0];
  const float* zj = (const float*)d_in[1];
  const int B = in_sizes[0] / D;  // 4096
  const int N = 2 * B;            // 8192

  __hip_bfloat16* zn = (__hip_bfloat16*)d_ws;
  float* denom = (float*)((char*)d_ws + (size_t)N * D * sizeof(__hip_bfloat16));
  float* pos = denom + N;
  unsigned* counter = (unsigned*)(pos + N);

  normalize_rows<<<512, 256, 0, stream>>>(zi, zj, zn, denom, counter, B);
  ntxent_gemm<<<NTILES, 256, 0, stream>>>(zn, denom, pos, counter,
                                          (float*)d_out, B);
}